// Round 1
// baseline (939.925 us; speedup 1.0000x reference)
//
#include <hip/hip_runtime.h>

typedef unsigned short u16;
using f32x4  = __attribute__((ext_vector_type(4))) float;
using bf16x8 = __attribute__((ext_vector_type(8))) __bf16;

// ---------- bf16 helpers (round-to-nearest-even split) ----------
__device__ __forceinline__ u16 f2bf(float f) {
  unsigned u = __builtin_bit_cast(unsigned, f);
  u += 0x7FFFu + ((u >> 16) & 1u);
  return (u16)(u >> 16);
}
__device__ __forceinline__ float bf2f(u16 h) {
  unsigned u = ((unsigned)h) << 16;
  return __builtin_bit_cast(float, u);
}

// async global->LDS, 16B per lane (wave-uniform base + lane*16 semantics)
__device__ __forceinline__ void gload_lds16(const void* g, void* l) {
  __builtin_amdgcn_global_load_lds((__attribute__((address_space(1))) void*)g,
                                   (__attribute__((address_space(3))) void*)l,
                                   16, 0, 0);
}

// ---------- split fp32 -> (bf16 hi, bf16 lo), vectorized x4 ----------
__global__ __launch_bounds__(256) void split_kernel(
    const float* __restrict__ x, u16* __restrict__ hi, u16* __restrict__ lo, int n4)
{
  const size_t t = (size_t)blockIdx.x * 256 + threadIdx.x;
  if (t >= (size_t)n4) return;
  float4 v = ((const float4*)x)[t];
  u16 h0 = f2bf(v.x), h1 = f2bf(v.y), h2 = f2bf(v.z), h3 = f2bf(v.w);
  u16 l0 = f2bf(v.x - bf2f(h0)), l1 = f2bf(v.y - bf2f(h1));
  u16 l2 = f2bf(v.z - bf2f(h2)), l3 = f2bf(v.w - bf2f(h3));
  uint2 hp, lp;
  hp.x = (unsigned)h0 | ((unsigned)h1 << 16);
  hp.y = (unsigned)h2 | ((unsigned)h3 << 16);
  lp.x = (unsigned)l0 | ((unsigned)l1 << 16);
  lp.y = (unsigned)l2 | ((unsigned)l3 << 16);
  ((uint2*)hi)[t] = hp;
  ((uint2*)lo)[t] = lp;
}

// ---------- split-bf16 NT GEMM: C[m,n] = sum_k A[m,k]*B[n,k] (+bias[n]) (+Cadd[m,n])
// 3 K-segments: Ah*Bh + Ah*Bl + Al*Bh  (lo*lo dropped, ~2^-16 relative) ----------
template<int BM, int BN>
__global__ __launch_bounds__(256) void gemm_split(
    const u16* __restrict__ Ah, const u16* __restrict__ Al,
    const u16* __restrict__ Bh, const u16* __restrict__ Bl,
    float* __restrict__ C, const float* __restrict__ bias,
    const float* __restrict__ Cadd, int M, int N, int K)
{
  constexpr int BK = 32;
  constexpr int WM = BM / 2, WN = BN / 2;
  constexpr int MT = WM / 16, NT = WN / 16;
  static_assert(BM % 64 == 0 && BN % 64 == 0, "tile divisibility");

  __shared__ __align__(16) u16 lA[BM * BK];
  __shared__ __align__(16) u16 lB[BN * BK];

  const int tid  = threadIdx.x;
  const int lane = tid & 63;
  const int wave = tid >> 6;
  const int wr   = wave >> 1, wc = wave & 1;
  const int m0   = blockIdx.x * BM;
  const int n0   = blockIdx.y * BN;
  const int quad = lane >> 4;
  const int l16  = lane & 15;

  const int arow = tid >> 2;          // 0..63
  const int acol = (tid & 3) * 8;     // 0,8,16,24
  const int nkt  = K / BK;

  f32x4 acc[MT][NT] = {};

  for (int seg = 0; seg < 3; ++seg) {
    const u16* As = (seg == 2) ? Al : Ah;
    const u16* Bs = (seg == 1) ? Bl : Bh;
    for (int kt = 0; kt < nkt; ++kt) {
      const int k0 = kt * BK;
      __syncthreads();
#pragma unroll
      for (int s = 0; s < BM / 64; ++s) {
        const u16* g = As + (size_t)(m0 + s * 64 + arow) * K + k0 + acol;
        gload_lds16(g, &lA[(s * 64 + arow) * BK + acol]);
      }
#pragma unroll
      for (int s = 0; s < BN / 64; ++s) {
        const u16* g = Bs + (size_t)(n0 + s * 64 + arow) * K + k0 + acol;
        gload_lds16(g, &lB[(s * 64 + arow) * BK + acol]);
      }
      __syncthreads();

      bf16x8 af[MT], bfv[NT];
#pragma unroll
      for (int i = 0; i < MT; ++i)
        af[i] = *(const bf16x8*)&lA[(wr * WM + i * 16 + l16) * BK + quad * 8];
#pragma unroll
      for (int j = 0; j < NT; ++j)
        bfv[j] = *(const bf16x8*)&lB[(wc * WN + j * 16 + l16) * BK + quad * 8];
#pragma unroll
      for (int i = 0; i < MT; ++i)
#pragma unroll
        for (int j = 0; j < NT; ++j)
          acc[i][j] = __builtin_amdgcn_mfma_f32_16x16x32_bf16(af[i], bfv[j], acc[i][j], 0, 0, 0);
    }
  }

  // epilogue: C/D layout col=lane&15 (N), row=quad*4+reg (M)
#pragma unroll
  for (int i = 0; i < MT; ++i) {
#pragma unroll
    for (int j = 0; j < NT; ++j) {
      const int gn = n0 + wc * WN + j * 16 + l16;
      const float bv = bias ? bias[gn] : 0.0f;
#pragma unroll
      for (int r = 0; r < 4; ++r) {
        const int gm = m0 + wr * WM + i * 16 + quad * 4 + r;
        float v = acc[i][j][r] + bv;
        if (Cadd) v += Cadd[(size_t)gm * N + gn];
        C[(size_t)gm * N + gn] = v;
      }
    }
  }
}

// ---------- sliding-window (127-wide) row sum of h (M x N), output split bf16 ----------
__global__ __launch_bounds__(256) void bandsum_kernel(
    const float* __restrict__ h, u16* __restrict__ sh, u16* __restrict__ sl, int M, int N)
{
  const int c = blockIdx.y * 256 + threadIdx.x;  // column
  const int R = blockIdx.x * 128;                // row stripe
  float s = 0.f;
  for (int k = R - 63; k < R + 63; ++k)
    if (k >= 0 && k < M) s += h[(size_t)k * N + c];
  for (int i = R; i < R + 128; ++i) {
    const int ka = i + 63;
    if (ka < M) s += h[(size_t)ka * N + c];
    const u16 hb = f2bf(s);
    sh[(size_t)i * N + c] = hb;
    sl[(size_t)i * N + c] = f2bf(s - bf2f(hb));
    const int kr = i - 63;
    if (kr >= 0) s -= h[(size_t)kr * N + c];
  }
}

// ---------- column softmax: partial online max/sum over row blocks ----------
__global__ __launch_bounds__(256) void colpart_kernel(
    const float* __restrict__ lg, float* __restrict__ pm, float* __restrict__ ps,
    int M, int N, int RB)
{
  const int j  = blockIdx.x * 256 + threadIdx.x;  // column
  const int rb = blockIdx.y;
  const int r0 = rb * RB;
  float m = -3.0e38f, s = 0.f;
  for (int i = r0; i < r0 + RB; ++i) {
    const float v = lg[(size_t)i * N + j];
    if (v <= m) {
      s += __expf(v - m);
    } else {
      s = s * __expf(m - v) + 1.0f;
      m = v;
    }
  }
  pm[(size_t)rb * N + j] = m;
  ps[(size_t)rb * N + j] = s;
}

__global__ __launch_bounds__(256) void colcombine_kernel(
    const float* __restrict__ pm, const float* __restrict__ ps,
    float* __restrict__ cv, int N, int nb)
{
  const int j = blockIdx.x * 256 + threadIdx.x;
  float m = -3.0e38f;
  for (int b = 0; b < nb; ++b) m = fmaxf(m, pm[(size_t)b * N + j]);
  float s = 0.f;
  for (int b = 0; b < nb; ++b) s += ps[(size_t)b * N + j] * __expf(pm[(size_t)b * N + j] - m);
  cv[j] = m + __logf(s);   // out = exp(v - cv[j])
}

__global__ __launch_bounds__(256) void norm_kernel(
    float* __restrict__ lg, const float* __restrict__ cv, int N)
{
  const size_t t = (size_t)blockIdx.x * 256 + threadIdx.x;
  float4 v = ((const float4*)lg)[t];
  const int j4 = (int)(t % (size_t)(N / 4));
  const float4 c = ((const float4*)cv)[j4];
  float4 o;
  o.x = __expf(v.x - c.x);
  o.y = __expf(v.y - c.y);
  o.z = __expf(v.z - c.z);
  o.w = __expf(v.w - c.w);
  ((float4*)lg)[t] = o;
}

extern "C" void kernel_launch(void* const* d_in, const int* in_sizes, int n_in,
                              void* d_out, int out_size, void* d_ws, size_t ws_size,
                              hipStream_t stream)
{
  const float* x1 = (const float*)d_in[0];
  const float* x2 = (const float*)d_in[1];
  const float* W1 = (const float*)d_in[2];
  const float* b1 = (const float*)d_in[3];
  const float* W2 = (const float*)d_in[4];
  const float* b2 = (const float*)d_in[5];
  const float* ga = (const float*)d_in[6];
  float* out = (float*)d_out;

  const int T = 4096, E = 512;

  // x-splits live in d_out (dead before lg is written there)
  u16* XH = (u16*)d_out;
  u16* XL = XH + (size_t)T * T;

  char* w = (char*)d_ws;
  u16* WH = (u16*)w;   w += (size_t)E * T * 2;
  u16* WL = (u16*)w;   w += (size_t)E * T * 2;
  float* h1 = (float*)w; w += (size_t)T * E * 4;
  float* h2 = (float*)w; w += (size_t)T * E * 4;
  u16* S1H = (u16*)w;  w += (size_t)T * E * 2;
  u16* S1L = (u16*)w;  w += (size_t)T * E * 2;
  u16* H2H = (u16*)w;  w += (size_t)T * E * 2;
  u16* H2L = (u16*)w;  w += (size_t)T * E * 2;
  float* pm = (float*)w; w += (size_t)32 * T * 4;
  float* ps = (float*)w; w += (size_t)32 * T * 4;
  float* cv = (float*)w; w += (size_t)T * 4;

  // h1 = x1 @ W1^T + b1
  split_kernel<<<T * T / 1024, 256, 0, stream>>>(x1, XH, XL, T * T / 4);
  split_kernel<<<E * T / 1024, 256, 0, stream>>>(W1, WH, WL, E * T / 4);
  gemm_split<128, 64><<<dim3(T / 128, E / 64), 256, 0, stream>>>(
      XH, XL, WH, WL, h1, b1, nullptr, T, E, T);

  // h2 = x2 @ W2^T + b2
  split_kernel<<<T * T / 1024, 256, 0, stream>>>(x2, XH, XL, T * T / 4);
  split_kernel<<<E * T / 1024, 256, 0, stream>>>(W2, WH, WL, E * T / 4);
  gemm_split<128, 64><<<dim3(T / 128, E / 64), 256, 0, stream>>>(
      XH, XL, WH, WL, h2, b2, nullptr, T, E, T);

  // S1 = band-sum(h1), split; h2 split
  bandsum_kernel<<<dim3(T / 128, E / 256), 256, 0, stream>>>(h1, S1H, S1L, T, E);
  split_kernel<<<T * E / 1024, 256, 0, stream>>>(h2, H2H, H2L, T * E / 4);

  // lg = S1 @ h2^T + global_att  (into d_out)
  gemm_split<128, 128><<<dim3(T / 128, T / 128), 256, 0, stream>>>(
      S1H, S1L, H2H, H2L, out, nullptr, ga, T, T, E);

  // softmax over axis 0 (per column), in-place on d_out
  colpart_kernel<<<dim3(T / 256, 32), 256, 0, stream>>>(out, pm, ps, T, T, 128);
  colcombine_kernel<<<T / 256, 256, 0, stream>>>(pm, ps, cv, T, 32);
  norm_kernel<<<T * T / 1024, 256, 0, stream>>>(out, cv, T);
}

// Round 2
// 681.730 us; speedup vs baseline: 1.3787x; 1.3787x over previous
//
#include <hip/hip_runtime.h>

typedef unsigned short u16;
using f32x4  = __attribute__((ext_vector_type(4))) float;
using bf16x8 = __attribute__((ext_vector_type(8))) __bf16;

// ---------- bf16 helpers ----------
__device__ __forceinline__ u16 f2bf(float f) {
  unsigned u = __builtin_bit_cast(unsigned, f);
  u += 0x7FFFu + ((u >> 16) & 1u);
  return (u16)(u >> 16);
}
__device__ __forceinline__ float bf2f(u16 h) {
  unsigned u = ((unsigned)h) << 16;
  return __builtin_bit_cast(float, u);
}

// pack two floats -> packed (hi bf16x2, lo bf16x2); RNE hi, trunc lo.
// residual |x - hi - lo| <= 2^-17 |x|
__device__ __forceinline__ void split2(float f0, float f1, unsigned& hi, unsigned& lo) {
  unsigned u0 = __builtin_bit_cast(unsigned, f0);
  unsigned u1 = __builtin_bit_cast(unsigned, f1);
  unsigned r0 = u0 + (0x7FFFu + ((u0 >> 16) & 1u));
  unsigned r1 = u1 + (0x7FFFu + ((u1 >> 16) & 1u));
  hi = (r0 >> 16) | (r1 & 0xFFFF0000u);
  float h0 = __builtin_bit_cast(float, r0 & 0xFFFF0000u);
  float h1 = __builtin_bit_cast(float, r1 & 0xFFFF0000u);
  unsigned l0 = __builtin_bit_cast(unsigned, f0 - h0);
  unsigned l1 = __builtin_bit_cast(unsigned, f1 - h1);
  lo = (l0 >> 16) | (l1 & 0xFFFF0000u);
}

// async global->LDS, 16B per lane (GEMM2 staging)
__device__ __forceinline__ void gload_lds16(const void* g, void* l) {
  __builtin_amdgcn_global_load_lds((__attribute__((address_space(1))) void*)g,
                                   (__attribute__((address_space(3))) void*)l,
                                   16, 0, 0);
}

// =====================================================================
// Fused GEMM1: h[:,0:512] = x1@W1^T (+b1), h[:,512:1024] = x2@W2^T (+b2)
// fp32 inputs converted to (hi,lo) bf16 in-kernel; 3 split segments per
// staged tile; split-K=2 into hp0/hp1 partial buffers (bias in z==0).
// grid (32, 8, 2), block 256.
// =====================================================================
#define LDSTR 40  // u16 row stride: 80 B -> rows 0..7 cover all 32 banks

__global__ __launch_bounds__(256, 2) void gemm_h(
    const float* __restrict__ x1, const float* __restrict__ x2,
    const float* __restrict__ W1, const float* __restrict__ W2,
    const float* __restrict__ b1, const float* __restrict__ b2,
    float* __restrict__ hp0, float* __restrict__ hp1)
{
  constexpr int K = 4096, NC = 1024, KC = 2048, BK = 32;
  __shared__ __align__(16) u16 lAh[128 * LDSTR];
  __shared__ __align__(16) u16 lAl[128 * LDSTR];
  __shared__ __align__(16) u16 lBh[128 * LDSTR];
  __shared__ __align__(16) u16 lBl[128 * LDSTR];

  const int tid  = threadIdx.x;
  const int lane = tid & 63;
  const int wave = tid >> 6;
  const int wr   = wave >> 1, wc = wave & 1;
  const int quad = lane >> 4;
  const int l16  = lane & 15;

  const int m0    = blockIdx.x * 128;
  const int n0    = blockIdx.y * 128;
  const int batch = (n0 >= 512) ? 1 : 0;
  const float* Ag   = batch ? x2 : x1;
  const float* Bg   = batch ? W2 : W1;
  const float* bias = batch ? b2 : b1;
  const int bn0  = n0 - batch * 512;
  const int z    = blockIdx.z;
  float* hp = z ? hp1 : hp0;
  const int k00 = z * KC;

  const int srow = tid >> 1;        // 0..127
  const int scol = (tid & 1) * 16;  // 0 or 16

  f32x4 acc[4][4] = {};

  const float* gA = Ag + (size_t)(m0 + srow) * K + k00 + scol;
  const float* gB = Bg + (size_t)(bn0 + srow) * K + k00 + scol;

  for (int kt = 0; kt < KC / BK; ++kt) {
    __syncthreads();
    {
      const float4* p = (const float4*)(gA + kt * BK);
      float4 v0 = p[0], v1 = p[1], v2 = p[2], v3 = p[3];
      uint4 h, l;
      split2(v0.x, v0.y, h.x, l.x); split2(v0.z, v0.w, h.y, l.y);
      split2(v1.x, v1.y, h.z, l.z); split2(v1.z, v1.w, h.w, l.w);
      *(uint4*)&lAh[srow * LDSTR + scol] = h;
      *(uint4*)&lAl[srow * LDSTR + scol] = l;
      split2(v2.x, v2.y, h.x, l.x); split2(v2.z, v2.w, h.y, l.y);
      split2(v3.x, v3.y, h.z, l.z); split2(v3.z, v3.w, h.w, l.w);
      *(uint4*)&lAh[srow * LDSTR + scol + 8] = h;
      *(uint4*)&lAl[srow * LDSTR + scol + 8] = l;
    }
    {
      const float4* p = (const float4*)(gB + kt * BK);
      float4 v0 = p[0], v1 = p[1], v2 = p[2], v3 = p[3];
      uint4 h, l;
      split2(v0.x, v0.y, h.x, l.x); split2(v0.z, v0.w, h.y, l.y);
      split2(v1.x, v1.y, h.z, l.z); split2(v1.z, v1.w, h.w, l.w);
      *(uint4*)&lBh[srow * LDSTR + scol] = h;
      *(uint4*)&lBl[srow * LDSTR + scol] = l;
      split2(v2.x, v2.y, h.x, l.x); split2(v2.z, v2.w, h.y, l.y);
      split2(v3.x, v3.y, h.z, l.z); split2(v3.z, v3.w, h.w, l.w);
      *(uint4*)&lBh[srow * LDSTR + scol + 8] = h;
      *(uint4*)&lBl[srow * LDSTR + scol + 8] = l;
    }
    __syncthreads();

    bf16x8 ah[4], al[4], bh[4], bl[4];
#pragma unroll
    for (int i = 0; i < 4; ++i) {
      ah[i] = *(const bf16x8*)&lAh[(wr * 64 + i * 16 + l16) * LDSTR + quad * 8];
      al[i] = *(const bf16x8*)&lAl[(wr * 64 + i * 16 + l16) * LDSTR + quad * 8];
    }
#pragma unroll
    for (int j = 0; j < 4; ++j) {
      bh[j] = *(const bf16x8*)&lBh[(wc * 64 + j * 16 + l16) * LDSTR + quad * 8];
      bl[j] = *(const bf16x8*)&lBl[(wc * 64 + j * 16 + l16) * LDSTR + quad * 8];
    }
#pragma unroll
    for (int i = 0; i < 4; ++i)
#pragma unroll
      for (int j = 0; j < 4; ++j) {
        acc[i][j] = __builtin_amdgcn_mfma_f32_16x16x32_bf16(ah[i], bh[j], acc[i][j], 0, 0, 0);
        acc[i][j] = __builtin_amdgcn_mfma_f32_16x16x32_bf16(ah[i], bl[j], acc[i][j], 0, 0, 0);
        acc[i][j] = __builtin_amdgcn_mfma_f32_16x16x32_bf16(al[i], bh[j], acc[i][j], 0, 0, 0);
      }
  }

  // epilogue: col = lane&15 (N), row = quad*4+reg (M)
#pragma unroll
  for (int i = 0; i < 4; ++i)
#pragma unroll
    for (int j = 0; j < 4; ++j) {
      const int gn = n0 + wc * 64 + j * 16 + l16;
      const float bv = (z == 0) ? bias[gn - batch * 512] : 0.0f;
#pragma unroll
      for (int r = 0; r < 4; ++r) {
        const int gm = m0 + wr * 64 + i * 16 + quad * 4 + r;
        hp[(size_t)gm * NC + gn] = acc[i][j][r] + bv;
      }
    }
}

// =====================================================================
// GEMM2 (unchanged from R1): split-bf16 NT GEMM with global_load_lds
// =====================================================================
template<int BM, int BN>
__global__ __launch_bounds__(256) void gemm_split(
    const u16* __restrict__ Ah, const u16* __restrict__ Al,
    const u16* __restrict__ Bh, const u16* __restrict__ Bl,
    float* __restrict__ C, const float* __restrict__ bias,
    const float* __restrict__ Cadd, int M, int N, int K)
{
  constexpr int BK = 32;
  constexpr int WM = BM / 2, WN = BN / 2;
  constexpr int MT = WM / 16, NT = WN / 16;

  __shared__ __align__(16) u16 lA[BM * BK];
  __shared__ __align__(16) u16 lB[BN * BK];

  const int tid  = threadIdx.x;
  const int lane = tid & 63;
  const int wave = tid >> 6;
  const int wr   = wave >> 1, wc = wave & 1;
  const int m0   = blockIdx.x * BM;
  const int n0   = blockIdx.y * BN;
  const int quad = lane >> 4;
  const int l16  = lane & 15;

  const int arow = tid >> 2;
  const int acol = (tid & 3) * 8;
  const int nkt  = K / BK;

  f32x4 acc[MT][NT] = {};

  for (int seg = 0; seg < 3; ++seg) {
    const u16* As = (seg == 2) ? Al : Ah;
    const u16* Bs = (seg == 1) ? Bl : Bh;
    for (int kt = 0; kt < nkt; ++kt) {
      const int k0 = kt * BK;
      __syncthreads();
#pragma unroll
      for (int s = 0; s < BM / 64; ++s) {
        const u16* g = As + (size_t)(m0 + s * 64 + arow) * K + k0 + acol;
        gload_lds16(g, &lA[(s * 64 + arow) * BK + acol]);
      }
#pragma unroll
      for (int s = 0; s < BN / 64; ++s) {
        const u16* g = Bs + (size_t)(n0 + s * 64 + arow) * K + k0 + acol;
        gload_lds16(g, &lB[(s * 64 + arow) * BK + acol]);
      }
      __syncthreads();

      bf16x8 af[MT], bfv[NT];
#pragma unroll
      for (int i = 0; i < MT; ++i)
        af[i] = *(const bf16x8*)&lA[(wr * WM + i * 16 + l16) * BK + quad * 8];
#pragma unroll
      for (int j = 0; j < NT; ++j)
        bfv[j] = *(const bf16x8*)&lB[(wc * WN + j * 16 + l16) * BK + quad * 8];
#pragma unroll
      for (int i = 0; i < MT; ++i)
#pragma unroll
        for (int j = 0; j < NT; ++j)
          acc[i][j] = __builtin_amdgcn_mfma_f32_16x16x32_bf16(af[i], bfv[j], acc[i][j], 0, 0, 0);
    }
  }

#pragma unroll
  for (int i = 0; i < MT; ++i)
#pragma unroll
    for (int j = 0; j < NT; ++j) {
      const int gn = n0 + wc * WN + j * 16 + l16;
      const float bv = bias ? bias[gn] : 0.0f;
#pragma unroll
      for (int r = 0; r < 4; ++r) {
        const int gm = m0 + wr * WM + i * 16 + quad * 4 + r;
        float v = acc[i][j][r] + bv;
        if (Cadd) v += Cadd[(size_t)gm * N + gn];
        C[(size_t)gm * N + gn] = v;
      }
    }
}

// ---------- sliding-window (127) row-sum of h1 = hp0+hp1 cols [0,512) ----------
__global__ __launch_bounds__(256) void bandsum_kernel(
    const float* __restrict__ hp0, const float* __restrict__ hp1,
    u16* __restrict__ sh, u16* __restrict__ sl, int M)
{
  const int c = blockIdx.y * 256 + threadIdx.x;  // 0..511
  const int R = blockIdx.x * 128;
  float s = 0.f;
  for (int k = R - 63; k < R + 63; ++k)
    if (k >= 0 && k < M) s += hp0[(size_t)k * 1024 + c] + hp1[(size_t)k * 1024 + c];
  for (int i = R; i < R + 128; ++i) {
    const int ka = i + 63;
    if (ka < M) s += hp0[(size_t)ka * 1024 + c] + hp1[(size_t)ka * 1024 + c];
    const u16 hb = f2bf(s);
    sh[(size_t)i * 512 + c] = hb;
    sl[(size_t)i * 512 + c] = f2bf(s - bf2f(hb));
    const int kr = i - 63;
    if (kr >= 0) s -= hp0[(size_t)kr * 1024 + c] + hp1[(size_t)kr * 1024 + c];
  }
}

// ---------- h2 = hp0+hp1 cols [512,1024) -> split bf16 ----------
__global__ __launch_bounds__(256) void h2split_kernel(
    const float* __restrict__ hp0, const float* __restrict__ hp1,
    u16* __restrict__ hh, u16* __restrict__ hl)
{
  const size_t t = (size_t)blockIdx.x * 256 + threadIdx.x;  // T*512/4 total
  const size_t row = t >> 7;
  const int c4 = (int)(t & 127) * 4;
  const float4 a = *(const float4*)&hp0[row * 1024 + 512 + c4];
  const float4 b = *(const float4*)&hp1[row * 1024 + 512 + c4];
  float v0 = a.x + b.x, v1 = a.y + b.y, v2 = a.z + b.z, v3 = a.w + b.w;
  u16 h0 = f2bf(v0), h1 = f2bf(v1), h2 = f2bf(v2), h3 = f2bf(v3);
  u16 l0 = f2bf(v0 - bf2f(h0)), l1 = f2bf(v1 - bf2f(h1));
  u16 l2 = f2bf(v2 - bf2f(h2)), l3 = f2bf(v3 - bf2f(h3));
  uint2 hp, lp;
  hp.x = (unsigned)h0 | ((unsigned)h1 << 16);
  hp.y = (unsigned)h2 | ((unsigned)h3 << 16);
  lp.x = (unsigned)l0 | ((unsigned)l1 << 16);
  lp.y = (unsigned)l2 | ((unsigned)l3 << 16);
  *(uint2*)&hh[row * 512 + c4] = hp;
  *(uint2*)&hl[row * 512 + c4] = lp;
}

// ---------- column softmax ----------
__global__ __launch_bounds__(256) void colpart_kernel(
    const float* __restrict__ lg, float* __restrict__ pm, float* __restrict__ ps,
    int M, int N, int RB)
{
  const int j  = blockIdx.x * 256 + threadIdx.x;
  const int rb = blockIdx.y;
  const int r0 = rb * RB;
  float m = -3.0e38f, s = 0.f;
  for (int i = r0; i < r0 + RB; ++i) {
    const float v = lg[(size_t)i * N + j];
    if (v <= m) {
      s += __expf(v - m);
    } else {
      s = s * __expf(m - v) + 1.0f;
      m = v;
    }
  }
  pm[(size_t)rb * N + j] = m;
  ps[(size_t)rb * N + j] = s;
}

__global__ __launch_bounds__(256) void colcombine_kernel(
    const float* __restrict__ pm, const float* __restrict__ ps,
    float* __restrict__ cv, int N, int nb)
{
  const int j = blockIdx.x * 256 + threadIdx.x;
  float m = -3.0e38f;
  for (int b = 0; b < nb; ++b) m = fmaxf(m, pm[(size_t)b * N + j]);
  float s = 0.f;
  for (int b = 0; b < nb; ++b) s += ps[(size_t)b * N + j] * __expf(pm[(size_t)b * N + j] - m);
  cv[j] = m + __logf(s);
}

__global__ __launch_bounds__(256) void norm_kernel(
    float* __restrict__ lg, const float* __restrict__ cv, int N)
{
  const size_t t = (size_t)blockIdx.x * 256 + threadIdx.x;
  float4 v = ((const float4*)lg)[t];
  const int j4 = (int)(t % (size_t)(N / 4));
  const float4 c = ((const float4*)cv)[j4];
  float4 o;
  o.x = __expf(v.x - c.x);
  o.y = __expf(v.y - c.y);
  o.z = __expf(v.z - c.z);
  o.w = __expf(v.w - c.w);
  ((float4*)lg)[t] = o;
}

extern "C" void kernel_launch(void* const* d_in, const int* in_sizes, int n_in,
                              void* d_out, int out_size, void* d_ws, size_t ws_size,
                              hipStream_t stream)
{
  const float* x1 = (const float*)d_in[0];
  const float* x2 = (const float*)d_in[1];
  const float* W1 = (const float*)d_in[2];
  const float* b1 = (const float*)d_in[3];
  const float* W2 = (const float*)d_in[4];
  const float* b2 = (const float*)d_in[5];
  const float* ga = (const float*)d_in[6];
  float* out = (float*)d_out;

  const int T = 4096, E = 512;

  // h split-K partials live in d_out (dead before lg is written there)
  float* hp0 = out;                        // 4096 x 1024
  float* hp1 = out + (size_t)T * 1024;     // 4096 x 1024

  char* w = (char*)d_ws;
  u16* S1H = (u16*)w;  w += (size_t)T * E * 2;
  u16* S1L = (u16*)w;  w += (size_t)T * E * 2;
  u16* H2H = (u16*)w;  w += (size_t)T * E * 2;
  u16* H2L = (u16*)w;  w += (size_t)T * E * 2;
  float* pm = (float*)w; w += (size_t)32 * T * 4;
  float* ps = (float*)w; w += (size_t)32 * T * 4;
  float* cv = (float*)w; w += (size_t)T * 4;

  // h1|h2 (4096 x 1024) = [x1@W1^T+b1 | x2@W2^T+b2], split-K partials
  gemm_h<<<dim3(T / 128, 8, 2), 256, 0, stream>>>(x1, x2, W1, W2, b1, b2, hp0, hp1);

  // S1 = band-sum(h1) -> split; h2 -> split
  bandsum_kernel<<<dim3(T / 128, 2), 256, 0, stream>>>(hp0, hp1, S1H, S1L, T);
  h2split_kernel<<<T * (E / 4) / 256, 256, 0, stream>>>(hp0, hp1, H2H, H2L);

  // lg = S1 @ h2^T + global_att  (into d_out)
  gemm_split<128, 128><<<dim3(T / 128, T / 128), 256, 0, stream>>>(
      S1H, S1L, H2H, H2L, out, nullptr, ga, T, T, E);

  // softmax over axis 0
  colpart_kernel<<<dim3(T / 256, 32), 256, 0, stream>>>(out, pm, ps, T, T, 128);
  colcombine_kernel<<<T / 256, 256, 0, stream>>>(pm, ps, cv, T, 32);
  norm_kernel<<<T * T / 1024, 256, 0, stream>>>(out, cv, T);
}